// Round 2
// baseline (774.340 us; speedup 1.0000x reference)
//
#include <hip/hip_runtime.h>
#include <cstddef>

// Problem constants (B=4096, H=1024, L=4)
#define BATCH 4096
#define HID   1024
#define NLAY  4
#define NG    4096   // 4*H  (gate rows of W)
#define KTOT  2048   // 2*H  (concat [x|h] contraction dim)

typedef short short8 __attribute__((ext_vector_type(8)));   // 8 bf16 in 4 VGPRs
typedef float f32x4  __attribute__((ext_vector_type(4)));

// fp32 -> bf16 round-to-nearest-even (inputs finite; no NaN handling needed)
__device__ __forceinline__ unsigned short f2bf(float f) {
    union { float f; unsigned u; } v; v.f = f;
    unsigned r = v.u + 0x7fffu + ((v.u >> 16) & 1u);
    return (unsigned short)(r >> 16);
}

__device__ __forceinline__ float sigm_f(float x) {
    return 1.0f / (1.0f + __expf(-x));          // x->-inf: 1/inf = 0, safe
}
__device__ __forceinline__ float tanh_f(float x) {
    // guarded symmetric form: e <= 1 always, no inf/inf NaN
    float e = __expf(-2.0f * fabsf(x));
    float r = (1.0f - e) / (1.0f + e);
    return copysignf(r, x);
}

// async global->LDS, 16B per lane. LDS dest is wave-uniform base + lane*16.
#define GLOAD_LDS16(g, l)                                                            \
    __builtin_amdgcn_global_load_lds(                                                \
        (const __attribute__((address_space(1))) void*)(g),                          \
        (__attribute__((address_space(3))) void*)(l), 16, 0, 0)

// ---------------------------------------------------------------------------
// Prep: pack weights [L][4H][2H] bf16 (cols 0..H-1 = W_ih, H..2H-1 = W_hh)
// ---------------------------------------------------------------------------
__global__ __launch_bounds__(256) void prep_weights(
    const float* __restrict__ Wih, const float* __restrict__ Whh,
    unsigned short* __restrict__ Wb)
{
    size_t t    = (size_t)blockIdx.x * 256 + threadIdx.x;
    size_t base = t * 4;                    // element index into [L*NG][KTOT]
    size_t row  = base >> 11;               // l*NG + n   (KTOT = 2^11)
    int    k    = (int)(base & (KTOT - 1));
    const float* src = (k < HID) ? (Wih + row * HID + k)
                                 : (Whh + row * HID + (k - HID));
    float4 v = *(const float4*)src;
    ushort4 o; o.x = f2bf(v.x); o.y = f2bf(v.y); o.z = f2bf(v.z); o.w = f2bf(v.w);
    *(ushort4*)(Wb + base) = o;
}

__global__ __launch_bounds__(256) void prep_bias(
    const float* __restrict__ bih, const float* __restrict__ bhh,
    float* __restrict__ bias)
{
    int i = blockIdx.x * 256 + threadIdx.x;   // L*NG = 16384 total
    bias[i] = bih[i] + bhh[i];
}

// A panels: A0 = [bf16(x) | bf16(h0[:,:,0])]; Al (l=1..3) h0-half = bf16(h0[:,:,l]).
// (h2-halves of A1..A3 are written by the fused GEMM epilogue.)
__global__ __launch_bounds__(256) void prep_A(
    const float* __restrict__ x, const float* __restrict__ h0,
    unsigned short* __restrict__ A0, unsigned short* __restrict__ A1,
    unsigned short* __restrict__ A2, unsigned short* __restrict__ A3)
{
    int idx = blockIdx.x * 256 + threadIdx.x;   // 0 .. B*H-1
    int b = idx >> 10, h = idx & (HID - 1);
    float4 hv = *(const float4*)(h0 + (size_t)idx * NLAY);   // h0[b,h,0..3]
    A0[(size_t)b * KTOT + h]       = f2bf(x[idx]);
    A0[(size_t)b * KTOT + HID + h] = f2bf(hv.x);
    A1[(size_t)b * KTOT + HID + h] = f2bf(hv.y);
    A2[(size_t)b * KTOT + HID + h] = f2bf(hv.z);
    A3[(size_t)b * KTOT + HID + h] = f2bf(hv.w);
}

// ---------------------------------------------------------------------------
// Fused GEMM + LSTM cell. 128x128 tile (M=batch x N=gate-cols), BK=64, 4 waves,
// mfma_f32_16x16x32_bf16, global_load_lds width-16 staging.
//
// N-tile column permutation: block-col c in [0,128) maps to
//   gate = (c>>4)&3,  hcol = bn*32 + (c>>6)*16 + (c&15)
// so within a wave, register subtile n == gate n for the SAME hcol
// (c = wn*64 + n*16 + lane15 -> c>>4 = wn*4+n -> gate = n; hcol = bn*32+wn*16+lane15).
// Each lane then holds i,f,g,o for its (b,h): full LSTM cell fused in epilogue.
// ---------------------------------------------------------------------------
__global__ __launch_bounds__(256, 2) void gemm_lstm_fused(
    const unsigned short* __restrict__ A,   // [BATCH][KTOT] bf16
    const unsigned short* __restrict__ W,   // [NG][KTOT] bf16, this layer
    const float* __restrict__ bias,         // [NG], this layer (bih+bhh)
    const float* __restrict__ c0,           // [B,H,L]
    float* __restrict__ outH,               // [B,H,L]
    float* __restrict__ outC,               // [B,H,L]
    unsigned short* __restrict__ Anext,     // next layer A panel or nullptr
    int layer)
{
    __shared__ unsigned short ldsA[128 * 64];
    __shared__ unsigned short ldsB[128 * 64];

    const int tid  = threadIdx.x;
    const int wave = tid >> 6;
    const int lane = tid & 63;
    const int bn = blockIdx.x, bm = blockIdx.y;
    const int wm = wave >> 1, wn = wave & 1;     // 2x2 waves -> 64x64 each

    f32x4 acc[4][4] = {};

    // --- staging addresses: each wave covers block rows wave*32..+32 ---
    const int srow8 = lane >> 3;              // row within an 8-row group
    const int scol  = (lane & 7) * 8;         // 8 bf16 = 16B per lane
    const unsigned short* Ag = A + (size_t)(bm * 128 + wave * 32 + srow8) * KTOT + scol;
    const unsigned short* Wg[4];
#pragma unroll
    for (int j = 0; j < 4; ++j) {
        int s    = wave * 32 + j * 8 + srow8;                       // block-col index
        int wrow = ((s >> 4) & 3) * HID + bn * 32 + (s >> 6) * 16 + (s & 15);
        Wg[j] = W + (size_t)wrow * KTOT + scol;
    }

    // LDS->frag: row = lane&15 (within 16-row subtile), kcol = (lane>>4)*8
    const int lrd = (lane & 15) * 64 + (lane >> 4) * 8;

    for (int k0 = 0; k0 < KTOT; k0 += 64) {
#pragma unroll
        for (int j = 0; j < 4; ++j) {
            GLOAD_LDS16(Ag + (size_t)(j * 8) * KTOT + k0, &ldsA[(wave * 32 + j * 8) * 64]);
            GLOAD_LDS16(Wg[j] + k0,                        &ldsB[(wave * 32 + j * 8) * 64]);
        }
        __syncthreads();
#pragma unroll
        for (int kk = 0; kk < 2; ++kk) {
            short8 af[4], bf[4];
#pragma unroll
            for (int m = 0; m < 4; ++m)
                af[m] = *(const short8*)&ldsA[(wm * 64 + m * 16) * 64 + lrd + kk * 32];
#pragma unroll
            for (int n = 0; n < 4; ++n)
                bf[n] = *(const short8*)&ldsB[(wn * 64 + n * 16) * 64 + lrd + kk * 32];
#pragma unroll
            for (int m = 0; m < 4; ++m)
#pragma unroll
                for (int n = 0; n < 4; ++n)
                    acc[m][n] = __builtin_amdgcn_mfma_f32_16x16x32_bf16(
                        af[m], bf[n], acc[m][n], 0, 0, 0);
        }
        __syncthreads();
    }

    // --- fused epilogue: acc[m][n] = gate n for hcol h, C/D layout per m89 ---
    const int h = bn * 32 + wn * 16 + (lane & 15);
    float bv[4];
#pragma unroll
    for (int n = 0; n < 4; ++n) bv[n] = bias[n * HID + h];

#pragma unroll
    for (int m = 0; m < 4; ++m) {
        const int b0 = bm * 128 + wm * 64 + m * 16 + ((lane >> 4) << 2);
#pragma unroll
        for (int r = 0; r < 4; ++r) {
            const int b = b0 + r;
            const size_t oi = ((size_t)b * HID + h) * NLAY + layer;
            float iv = sigm_f(acc[m][0][r] + bv[0]);
            float fv = sigm_f(acc[m][1][r] + bv[1]);
            float gv = tanh_f(acc[m][2][r] + bv[2]);
            float ov = sigm_f(acc[m][3][r] + bv[3]);
            float c2 = fv * c0[oi] + iv * gv;
            float h2 = ov * tanh_f(c2);
            outH[oi] = h2;
            outC[oi] = c2;
            if (Anext) Anext[(size_t)b * KTOT + h] = f2bf(h2);
        }
    }
}

// ---------------------------------------------------------------------------
// Launch. ws layout (16B aligned), total ~128 MB:
//   [0)              Wb   : L*NG*KTOT bf16   = 67,108,864 B
//   [67108864)       bias : L*NG fp32        =     65,536 B
//   [67174400)       A0   : BATCH*KTOT bf16  = 16,777,216 B
//   [83951616)       A1
//   [100728832)      A2
//   [117506048)      A3                      (end 134,283,264 B)
// ---------------------------------------------------------------------------
extern "C" void kernel_launch(void* const* d_in, const int* in_sizes, int n_in,
                              void* d_out, int out_size, void* d_ws, size_t ws_size,
                              hipStream_t stream)
{
    const float* x   = (const float*)d_in[0];
    const float* h0  = (const float*)d_in[1];
    const float* c0  = (const float*)d_in[2];
    const float* Wih = (const float*)d_in[3];
    const float* Whh = (const float*)d_in[4];
    const float* bih = (const float*)d_in[5];
    const float* bhh = (const float*)d_in[6];

    float* outH = (float*)d_out;
    float* outC = outH + (size_t)BATCH * HID * NLAY;

    char* ws = (char*)d_ws;
    unsigned short* Wb   = (unsigned short*)(ws);
    float*          bias = (float*)(ws + 67108864);
    unsigned short* Ap[4];
    Ap[0] = (unsigned short*)(ws + 67174400);
    Ap[1] = (unsigned short*)(ws + 83951616);
    Ap[2] = (unsigned short*)(ws + 100728832);
    Ap[3] = (unsigned short*)(ws + 117506048);

    // prep (independent)
    prep_weights<<<32768, 256, 0, stream>>>(Wih, Whh, Wb);   // L*NG*KTOT/4/256
    prep_bias<<<64, 256, 0, stream>>>(bih, bhh, bias);
    prep_A<<<BATCH * HID / 256, 256, 0, stream>>>(x, h0, Ap[0], Ap[1], Ap[2], Ap[3]);

    for (int l = 0; l < NLAY; ++l) {
        gemm_lstm_fused<<<dim3(HID / 32, BATCH / 128), 256, 0, stream>>>(
            Ap[l], Wb + (size_t)l * NG * KTOT, bias + l * NG, c0,
            outH, outC, (l < NLAY - 1) ? Ap[l + 1] : nullptr, l);
    }
}

// Round 7
// 683.146 us; speedup vs baseline: 1.1335x; 1.1335x over previous
//
#include <hip/hip_runtime.h>
#include <cstddef>

// Problem constants (B=4096, H=1024, L=4)
#define BATCH 4096
#define HID   1024
#define NLAY  4
#define NG    4096   // 4*H  (gate rows of W)
#define KTOT  2048   // 2*H  (concat [x|h] contraction dim)
#define BH    (BATCH * HID)   // 4,194,304

typedef short short8 __attribute__((ext_vector_type(8)));   // 8 bf16 in 4 VGPRs
typedef float f32x4  __attribute__((ext_vector_type(4)));

// fp32 -> bf16 round-to-nearest-even (inputs finite; no NaN handling needed)
__device__ __forceinline__ unsigned short f2bf(float f) {
    union { float f; unsigned u; } v; v.f = f;
    unsigned r = v.u + 0x7fffu + ((v.u >> 16) & 1u);
    return (unsigned short)(r >> 16);
}

__device__ __forceinline__ float sigm_f(float x) {
    return 1.0f / (1.0f + __expf(-x));          // x->-inf: 1/inf = 0, safe
}
__device__ __forceinline__ float tanh_f(float x) {
    // guarded symmetric form: e <= 1 always, no inf/inf NaN
    float e = __expf(-2.0f * fabsf(x));
    float r = (1.0f - e) / (1.0f + e);
    return copysignf(r, x);
}

// async global->LDS, 16B per lane. LDS dest is wave-uniform base + lane*16.
#define GLOAD_LDS16(g, l)                                                            \
    __builtin_amdgcn_global_load_lds(                                                \
        (const __attribute__((address_space(1))) void*)(g),                          \
        (__attribute__((address_space(3))) void*)(l), 16, 0, 0)

// ---------------------------------------------------------------------------
// Prep: pack weights [L][4H][2H] bf16 (cols 0..H-1 = W_ih, H..2H-1 = W_hh)
// ---------------------------------------------------------------------------
__global__ __launch_bounds__(256) void prep_weights(
    const float* __restrict__ Wih, const float* __restrict__ Whh,
    unsigned short* __restrict__ Wb)
{
    size_t t    = (size_t)blockIdx.x * 256 + threadIdx.x;
    size_t base = t * 4;                    // element index into [L*NG][KTOT]
    size_t row  = base >> 11;               // l*NG + n   (KTOT = 2^11)
    int    k    = (int)(base & (KTOT - 1));
    const float* src = (k < HID) ? (Wih + row * HID + k)
                                 : (Whh + row * HID + (k - HID));
    float4 v = *(const float4*)src;
    ushort4 o; o.x = f2bf(v.x); o.y = f2bf(v.y); o.z = f2bf(v.z); o.w = f2bf(v.w);
    *(ushort4*)(Wb + base) = o;
}

__global__ __launch_bounds__(256) void prep_bias(
    const float* __restrict__ bih, const float* __restrict__ bhh,
    float* __restrict__ bias)
{
    int i = blockIdx.x * 256 + threadIdx.x;   // L*NG = 16384 total
    bias[i] = bih[i] + bhh[i];
}

// Per-(b,h) prep: A-panel halves (bf16) and, if cc!=nullptr, a layer-major
// contiguous copy of c0: cc[l][b*H+h] = c0[b,h,l] (overwritten in place with c2).
__global__ __launch_bounds__(256) void prep_misc(
    const float* __restrict__ x, const float* __restrict__ h0,
    const float* __restrict__ c0,
    unsigned short* __restrict__ A0, unsigned short* __restrict__ A1,
    unsigned short* __restrict__ A2, unsigned short* __restrict__ A3,
    float* __restrict__ cc)
{
    int idx = blockIdx.x * 256 + threadIdx.x;   // 0 .. B*H-1
    int b = idx >> 10, h = idx & (HID - 1);
    float4 hv = *(const float4*)(h0 + (size_t)idx * NLAY);   // h0[b,h,0..3]
    A0[(size_t)b * KTOT + h]       = f2bf(x[idx]);
    A0[(size_t)b * KTOT + HID + h] = f2bf(hv.x);
    A1[(size_t)b * KTOT + HID + h] = f2bf(hv.y);
    A2[(size_t)b * KTOT + HID + h] = f2bf(hv.z);
    A3[(size_t)b * KTOT + HID + h] = f2bf(hv.w);
    if (cc) {
        float4 cv = *(const float4*)(c0 + (size_t)idx * NLAY);
        cc[idx]          = cv.x;
        cc[BH + idx]     = cv.y;
        cc[2 * BH + idx] = cv.z;
        cc[3 * BH + idx] = cv.w;
    }
}

// ---------------------------------------------------------------------------
// Fused GEMM + LSTM cell. 128x128 tile (M=batch x N=gate-cols), BK=64, 4 waves,
// mfma_f32_16x16x32_bf16, global_load_lds width-16 staging.
//
// N-tile column permutation (HW-verified round 2): block-col c in [0,128) maps
// to gate=(c>>4)&3, hcol=bn*32+(c>>6)*16+(c&15), so register subtile n == gate
// n for the SAME hcol; each lane holds i,f,g,o for its (b,h) -> full LSTM cell
// fused in epilogue.
//
// LDS XOR-swizzle (T2 / rule #21): tiles are [128 rows][8 slots of 16B].
// Linear layout is a 16-way bank conflict (128B row stride). Data of logical
// slot s of row r lives at physical slot s^(r&7):
//   - write side: global_load_lds dest stays LINEAR; the per-lane GLOBAL source
//     slot is XORed instead (involution within one 128B row -> coalescing
//     unchanged; row&7 == lane>>3 exactly, since all row offsets are mult-of-8),
//   - read side: ds_read slot = (logical slot) ^ (row&7), row&7 == lane&7.
//   8 consecutive rows hit 8 distinct 16B slots = all 32 banks; residual 2-way
//   (lane vs lane+8) is free per m136.
//
// LM=true : epilogue I/O layer-major contiguous (cin/cout/hout are [BH] slabs);
//           cin/cout intentionally alias (in-place, same-thread same-address
//           RMW) -> they are NOT declared __restrict__.
// LM=false: round-2 strided [B,H,L] epilogue (ws-size fallback).
// ---------------------------------------------------------------------------
template<bool LM>
__global__ __launch_bounds__(256, 2) void gemm_lstm_fused(
    const unsigned short* __restrict__ A,   // [BATCH][KTOT] bf16
    const unsigned short* __restrict__ W,   // [NG][KTOT] bf16, this layer
    const float* __restrict__ bias,         // [NG], this layer (bih+bhh)
    const float* cin,                       // LM ? cc_l [BH] : c0 [B,H,L]  (may alias cout!)
    float* cout,                            // LM ? cc_l [BH] : outC [B,H,L]
    float* __restrict__ hout,               // LM ? hT_l [BH] : outH [B,H,L]
    unsigned short* __restrict__ Anext,     // next layer A panel or nullptr
    int layer)
{
    __shared__ unsigned short ldsA[128 * 64];
    __shared__ unsigned short ldsB[128 * 64];

    const int tid  = threadIdx.x;
    const int wave = tid >> 6;
    const int lane = tid & 63;
    const int bn = blockIdx.x, bm = blockIdx.y;
    const int wm = wave >> 1, wn = wave & 1;     // 2x2 waves -> 64x64 each

    f32x4 acc[4][4] = {};

    // --- staging: each wave covers block rows wave*32..+32; row&7 == lane>>3 ---
    const int srow8 = lane >> 3;                        // 0..7
    const int scol  = (((lane & 7) ^ srow8) << 3);      // XOR-swizzled source slot
    const unsigned short* Ag = A + (size_t)(bm * 128 + wave * 32 + srow8) * KTOT + scol;
    const unsigned short* Wg[4];
#pragma unroll
    for (int j = 0; j < 4; ++j) {
        int s    = wave * 32 + j * 8 + srow8;                       // block-col index
        int wrow = ((s >> 4) & 3) * HID + bn * 32 + (s >> 6) * 16 + (s & 15);
        Wg[j] = W + (size_t)wrow * KTOT + scol;
    }

    // --- LDS->frag read: row = lane&15 within 16-row subtile, key = row&7 ---
    const int rrow = lane & 15;
    const int rkey = lane & 7;                          // == rrow & 7

    for (int k0 = 0; k0 < KTOT; k0 += 64) {
#pragma unroll
        for (int j = 0; j < 4; ++j) {
            GLOAD_LDS16(Ag + (size_t)(j * 8) * KTOT + k0, &ldsA[(wave * 32 + j * 8) * 64]);
            GLOAD_LDS16(Wg[j] + k0,                        &ldsB[(wave * 32 + j * 8) * 64]);
        }
        __syncthreads();
#pragma unroll
        for (int kk = 0; kk < 2; ++kk) {
            const int ro = ((((lane >> 4) + kk * 4) ^ rkey) << 3);  // swizzled slot
            short8 af[4], bf[4];
#pragma unroll
            for (int m = 0; m < 4; ++m)
                af[m] = *(const short8*)&ldsA[(wm * 64 + m * 16 + rrow) * 64 + ro];
#pragma unroll
            for (int n = 0; n < 4; ++n)
                bf[n] = *(const short8*)&ldsB[(wn * 64 + n * 16 + rrow) * 64 + ro];
#pragma unroll
            for (int m = 0; m < 4; ++m)
#pragma unroll
                for (int n = 0; n < 4; ++n)
                    acc[m][n] = __builtin_amdgcn_mfma_f32_16x16x32_bf16(
                        af[m], bf[n], acc[m][n], 0, 0, 0);
        }
        __syncthreads();
    }

    // --- fused epilogue: acc[m][n] = gate n for hcol h, C/D layout per m89 ---
    const int h = bn * 32 + wn * 16 + (lane & 15);
    float bv[4];
#pragma unroll
    for (int n = 0; n < 4; ++n) bv[n] = bias[n * HID + h];

#pragma unroll
    for (int m = 0; m < 4; ++m) {
        const int b0 = bm * 128 + wm * 64 + m * 16 + ((lane >> 4) << 2);
#pragma unroll
        for (int r = 0; r < 4; ++r) {
            const int b = b0 + r;
            const size_t idx2 = LM ? ((size_t)b * HID + h)
                                   : (((size_t)b * HID + h) * NLAY + layer);
            float iv = sigm_f(acc[m][0][r] + bv[0]);
            float fv = sigm_f(acc[m][1][r] + bv[1]);
            float gv = tanh_f(acc[m][2][r] + bv[2]);
            float ov = sigm_f(acc[m][3][r] + bv[3]);
            float c2 = fv * cin[idx2] + iv * gv;    // LM: in-place same-thread RMW
            float h2 = ov * tanh_f(c2);
            cout[idx2] = c2;
            hout[idx2] = h2;
            if (Anext) Anext[(size_t)b * KTOT + h] = f2bf(h2);
        }
    }
}

// ---------------------------------------------------------------------------
// Final interleave: layer-major hT/cc -> [B,H,L] float4-coalesced outputs.
// ---------------------------------------------------------------------------
__global__ __launch_bounds__(256) void interleave(
    const float* __restrict__ hT, const float* __restrict__ cc,
    float* __restrict__ outH, float* __restrict__ outC)
{
    int idx = blockIdx.x * 256 + threadIdx.x;   // 0 .. B*H-1
    float4 hv = { hT[idx], hT[BH + idx], hT[2 * BH + idx], hT[3 * BH + idx] };
    float4 cv = { cc[idx], cc[BH + idx], cc[2 * BH + idx], cc[3 * BH + idx] };
    *(float4*)(outH + (size_t)idx * NLAY) = hv;
    *(float4*)(outC + (size_t)idx * NLAY) = cv;
}

// ---------------------------------------------------------------------------
// Launch. ws layout (16B aligned):
//   [0)           Wb   : L*NG*KTOT bf16   = 67,108,864
//   [67108864)    bias : L*NG fp32        =     65,536
//   [67174400)    A0..A3 : 4 * 16,777,216 = 67,108,864   (end 134,283,264)
//   -- layer-major staging (only if ws_size allows):
//   [134283264)   cc   : 4 * BH fp32      = 67,108,864   (c0 in, c2 out, in place)
//   [201392128)   hT   : 4 * BH fp32      = 67,108,864   (end 268,500,992)
// ws_size is a per-problem constant -> branch is deterministic (graph-safe).
// ---------------------------------------------------------------------------
extern "C" void kernel_launch(void* const* d_in, const int* in_sizes, int n_in,
                              void* d_out, int out_size, void* d_ws, size_t ws_size,
                              hipStream_t stream)
{
    const float* x   = (const float*)d_in[0];
    const float* h0  = (const float*)d_in[1];
    const float* c0  = (const float*)d_in[2];
    const float* Wih = (const float*)d_in[3];
    const float* Whh = (const float*)d_in[4];
    const float* bih = (const float*)d_in[5];
    const float* bhh = (const float*)d_in[6];

    float* outH = (float*)d_out;
    float* outC = outH + (size_t)BH * NLAY;

    char* ws = (char*)d_ws;
    unsigned short* Wb   = (unsigned short*)(ws);
    float*          bias = (float*)(ws + 67108864);
    unsigned short* Ap[4];
    Ap[0] = (unsigned short*)(ws + 67174400);
    Ap[1] = (unsigned short*)(ws + 83951616);
    Ap[2] = (unsigned short*)(ws + 100728832);
    Ap[3] = (unsigned short*)(ws + 117506048);

    const bool lm = (ws_size >= 268500992ULL);
    float* cc = lm ? (float*)(ws + 134283264) : nullptr;
    float* hT = lm ? (float*)(ws + 201392128) : nullptr;

    // prep (independent)
    prep_weights<<<32768, 256, 0, stream>>>(Wih, Whh, Wb);   // L*NG*KTOT/4/256
    prep_bias<<<64, 256, 0, stream>>>(bih, bhh, bias);
    prep_misc<<<BH / 256, 256, 0, stream>>>(x, h0, c0,
                                            Ap[0], Ap[1], Ap[2], Ap[3], cc);

    const dim3 grid(HID / 32, BATCH / 128);
    for (int l = 0; l < NLAY; ++l) {
        unsigned short* An = (l < NLAY - 1) ? Ap[l + 1] : nullptr;
        const unsigned short* Wl = Wb + (size_t)l * NG * KTOT;
        const float* bl = bias + l * NG;
        if (lm) {
            gemm_lstm_fused<true><<<grid, 256, 0, stream>>>(
                Ap[l], Wl, bl, cc + (size_t)l * BH, cc + (size_t)l * BH,
                hT + (size_t)l * BH, An, l);
        } else {
            gemm_lstm_fused<false><<<grid, 256, 0, stream>>>(
                Ap[l], Wl, bl, c0, outC, outH, An, l);
        }
    }

    if (lm) interleave<<<BH / 256, 256, 0, stream>>>(hT, cc, outH, outC);
}